// Round 5
// baseline (412.257 us; speedup 1.0000x reference)
//
#include <hip/hip_runtime.h>
#include <hip/hip_cooperative_groups.h>
#include <math.h>

namespace cg = cooperative_groups;

#define BB 8
#define NN 2048
#define IN_DIM 256
#define OUT_DIM 128
#define M_TOT (BB*NN)          // 16384
#define CHUNK 32
#define NCHUNK (NN/CHUNK)      // 64
#define NBLK 256               // cooperative blocks (1/CU guaranteed)
#define BM 32                  // gemm rows per virtual block

// ---------------- workspace layout (in floats) ----------------
static const size_t OFF_H    = 0;                                   // h: M_TOT*128
static const size_t OFF_SRC  = OFF_H   + (size_t)M_TOT*OUT_DIM;
static const size_t OFF_DST  = OFF_SRC + M_TOT;
static const size_t OFF_SD   = OFF_DST + M_TOT;                     // sorted_d
static const size_t OFF_SI   = OFF_SD  + M_TOT;                     // sorted_idx (int)
static const size_t OFF_WP   = OFF_SI  + M_TOT;                     // wpos (sorted order)
static const size_t OFF_WN   = OFF_WP  + M_TOT;                     // wneg
static const size_t OFF_CP   = OFF_WN  + M_TOT;                     // chunk sums
static const size_t OFF_CN   = OFF_CP  + (size_t)BB*NCHUNK*OUT_DIM;
static const size_t OFF_CPW  = OFF_CN  + (size_t)BB*NCHUNK*OUT_DIM;
static const size_t OFF_CNW  = OFF_CPW + BB*NCHUNK;
static const size_t OFF_PREH = OFF_CNW + BB*NCHUNK;                 // 8*2049*128
static const size_t OFF_SUFH = OFF_PREH + (size_t)BB*(NN+1)*OUT_DIM;
static const size_t OFF_PREW = OFF_SUFH + (size_t)BB*(NN+1)*OUT_DIM;
static const size_t OFF_SUFW = OFF_PREW + (size_t)BB*(NN+1);
static const size_t OFF_RP   = OFF_SUFW + (size_t)BB*(NN+1);        // fallback rank partials

// ================================================================
// Fused cooperative kernel: 256 blocks x 512 threads.
// Each block = 2 "virtual blocks" (halves u=0/1 of 256 threads).
// ================================================================
union SharedU {
    struct {                         // P1 gemm (~33.8 KB)
        float xs[2][32][34];         // per-half x tile [k][m], padded
        float wsh[32][132];          // shared W tile [k][o], padded
        float redS[2][32][16];
        float redD[2][32][16];
    } g;
    struct {                         // P2 rank (~10.2 KB)
        float ld[NN];                // shared (both halves same batch)
        int   red[2][32][8];
    } r;
    struct {                         // P3/P4 (~33.5 KB)
        float hs[2][CHUNK][OUT_DIM];
        float wn[2][CHUNK];
        float wp[2][CHUNK];
        int   si[2][CHUNK];
    } s;
    struct {                         // P5 query (~9.2 KB)
        float sd[NN];                // shared (same batch)
        int   lo[2][32];
        float pe[2][32], pn[2][32], sc[2][32];
    } q;
};

__global__ __launch_bounds__(512, 2) void fused_gat_kernel(
    const float* __restrict__ x, const int* __restrict__ mask,
    const float* __restrict__ W, const float* __restrict__ a_src,
    const float* __restrict__ a_dst,
    float* __restrict__ h, float* __restrict__ src, float* __restrict__ dstv,
    float* __restrict__ sorted_d, int* __restrict__ sidx,
    float* __restrict__ wpos, float* __restrict__ wneg,
    float* __restrict__ cPos, float* __restrict__ cNeg,
    float* __restrict__ cPosW, float* __restrict__ cNegW,
    float* __restrict__ PreH, float* __restrict__ SufH,
    float* __restrict__ PreW, float* __restrict__ SufW,
    float* __restrict__ out)
{
    cg::grid_group grid = cg::this_grid();
    const int tid = threadIdx.x;
    const int u   = tid >> 8;          // half 0/1
    const int t2  = tid & 255;         // tid within half
    const int vb  = blockIdx.x * 2 + u;  // virtual block 0..511
    __shared__ SharedU sh;

    // ================= P1: h = x @ W^T (+ src/dst dots) =================
    {
        const int m0 = vb * BM;
        const int mt = t2 >> 4;        // 0..15 -> 2 rows each
        const int ot = t2 & 15;        // 0..15 -> 8 cols each
        float acc[2][8];
#pragma unroll
        for (int i = 0; i < 2; ++i)
#pragma unroll
            for (int j = 0; j < 8; ++j) acc[i][j] = 0.f;

        const float4* x4 = (const float4*)x;
        const float4* W4 = (const float4*)W;

        for (int k0 = 0; k0 < IN_DIM; k0 += 32) {
            {   // per-half x tile: 32 rows x 32 k, transposed -> xs[u][k][m]
                int row = t2 >> 3, c4 = t2 & 7;
                float4 v = x4[(size_t)(m0 + row) * (IN_DIM / 4) + (k0 >> 2) + c4];
                sh.g.xs[u][c4 * 4 + 0][row] = v.x; sh.g.xs[u][c4 * 4 + 1][row] = v.y;
                sh.g.xs[u][c4 * 4 + 2][row] = v.z; sh.g.xs[u][c4 * 4 + 3][row] = v.w;
            }
#pragma unroll
            for (int it = 0; it < 2; ++it) {   // shared W tile: 128 o x 32 k
                int idx = tid + it * 512;
                int o = idx >> 3, cw = idx & 7;
                float4 v = W4[(size_t)o * (IN_DIM / 4) + (k0 >> 2) + cw];
                sh.g.wsh[cw * 4 + 0][o] = v.x; sh.g.wsh[cw * 4 + 1][o] = v.y;
                sh.g.wsh[cw * 4 + 2][o] = v.z; sh.g.wsh[cw * 4 + 3][o] = v.w;
            }
            __syncthreads();
#pragma unroll
            for (int k = 0; k < 32; ++k) {
                float2 xv = *(const float2*)&sh.g.xs[u][k][mt * 2];
                float4 wa = *(const float4*)&sh.g.wsh[k][ot * 8];
                float4 wb = *(const float4*)&sh.g.wsh[k][ot * 8 + 4];
                float xm[2] = {xv.x, xv.y};
                float wv[8] = {wa.x, wa.y, wa.z, wa.w, wb.x, wb.y, wb.z, wb.w};
#pragma unroll
                for (int i = 0; i < 2; ++i)
#pragma unroll
                    for (int j = 0; j < 8; ++j)
                        acc[i][j] = fmaf(xm[i], wv[j], acc[i][j]);
            }
            __syncthreads();
        }

        float as8[8], ad8[8];
#pragma unroll
        for (int j = 0; j < 8; ++j) { as8[j] = a_src[ot * 8 + j]; ad8[j] = a_dst[ot * 8 + j]; }
#pragma unroll
        for (int i = 0; i < 2; ++i) {
            int m = m0 + mt * 2 + i;
            float4 v0 = {acc[i][0], acc[i][1], acc[i][2], acc[i][3]};
            float4 v1 = {acc[i][4], acc[i][5], acc[i][6], acc[i][7]};
            ((float4*)h)[(size_t)m * (OUT_DIM / 4) + ot * 2 + 0] = v0;
            ((float4*)h)[(size_t)m * (OUT_DIM / 4) + ot * 2 + 1] = v1;
            float ps = 0.f, pd = 0.f;
#pragma unroll
            for (int j = 0; j < 8; ++j) {
                ps = fmaf(acc[i][j], as8[j], ps);
                pd = fmaf(acc[i][j], ad8[j], pd);
            }
            sh.g.redS[u][mt * 2 + i][ot] = ps;
            sh.g.redD[u][mt * 2 + i][ot] = pd;
        }
        __syncthreads();
        if (t2 < BM) {
            float ss = 0.f, dd = 0.f;
#pragma unroll
            for (int t = 0; t < 16; ++t) { ss += sh.g.redS[u][t2][t]; dd += sh.g.redD[u][t2][t]; }
            src[m0 + t2] = ss;
            dstv[m0 + t2] = dd;
        }
    }
    __threadfence();
    grid.sync();

    // ================= P2: rank + scatter + weights =================
    {
        const int b  = blockIdx.x >> 5;    // 32 blocks per batch
        const int jg = vb & 63;            // group of 32 j
        for (int i = tid; i < NN; i += 512) sh.r.ld[i] = dstv[b * NN + i];
        __syncthreads();
        const int js = t2 >> 3;            // 0..31
        const int qq = t2 & 7;             // 8 threads per j
        const int jloc = jg * 32 + js;
        float myd = sh.r.ld[jloc];
        const float4* l4 = (const float4*)sh.r.ld;
        int rank = 0;
#pragma unroll 8
        for (int t = 0; t < 64; ++t) {
            float4 v = l4[qq * 64 + t];
            int jj = qq * 256 + t * 4;
            rank += (v.x < myd) || (v.x == myd && jj + 0 < jloc);
            rank += (v.y < myd) || (v.y == myd && jj + 1 < jloc);
            rank += (v.z < myd) || (v.z == myd && jj + 2 < jloc);
            rank += (v.w < myd) || (v.w == myd && jj + 3 < jloc);
        }
        sh.r.red[u][js][qq] = rank;
        __syncthreads();
        if (t2 < 32) {
            int j = jg * 32 + t2;
            const int* rr = sh.r.red[u][t2];
            int rk = rr[0] + rr[1] + rr[2] + rr[3] + rr[4] + rr[5] + rr[6] + rr[7];
            float d = sh.r.ld[j];
            int mk = mask[b * NN + j];
            sorted_d[b * NN + rk] = d;
            sidx[b * NN + rk]     = j;
            wpos[b * NN + rk] = mk ? expf(d) : 0.f;
            wneg[b * NN + rk] = mk ? expf(0.2f * d) : 0.f;
        }
    }
    __threadfence();
    grid.sync();

    // ================= P3: chunk stage + sums ===== P4: expand =================
    {
        const int b  = blockIdx.x >> 5;
        const int c  = vb & 63;
        const int cidx = vb;               // == b*NCHUNK + c
        const int r0 = c * CHUNK;
        const size_t hb = (size_t)b * NN;
        const size_t pb = (size_t)b * (NN + 1);

        if (t2 < CHUNK) {
            int rr = b * NN + r0 + t2;
            sh.s.si[u][t2] = sidx[rr];
            sh.s.wn[u][t2] = wneg[rr];
            sh.s.wp[u][t2] = wpos[rr];
        }
        __syncthreads();
#pragma unroll
        for (int it = 0; it < 4; ++it) {   // stage 32 gathered h rows per half
            int row = it * 8 + (t2 >> 5);
            int c4 = t2 & 31;
            float4 v = ((const float4*)h)[(hb + sh.s.si[u][row]) * (OUT_DIM / 4) + c4];
            *(float4*)&sh.s.hs[u][row][c4 * 4] = v;
        }
        __syncthreads();

        if (t2 < 128) {
            float an = 0.f;
#pragma unroll
            for (int r = 0; r < CHUNK; ++r) an = fmaf(sh.s.wn[u][r], sh.s.hs[u][r][t2], an);
            cNeg[(size_t)cidx * OUT_DIM + t2] = an;
        } else {
            int o = t2 - 128;
            float ap = 0.f;
#pragma unroll
            for (int r = 0; r < CHUNK; ++r) ap = fmaf(sh.s.wp[u][r], sh.s.hs[u][r][o], ap);
            cPos[(size_t)cidx * OUT_DIM + o] = ap;
        }
        if (t2 == 0)   { float a = 0.f; for (int r = 0; r < CHUNK; ++r) a += sh.s.wn[u][r]; cNegW[cidx] = a; }
        if (t2 == 128) { float a = 0.f; for (int r = 0; r < CHUNK; ++r) a += sh.s.wp[u][r]; cPosW[cidx] = a; }

        __threadfence();
        grid.sync();     // all chunk sums visible; hs/wn/wp persist in LDS

        if (t2 < 128) {
            int o = t2;
            float acc = 0.f;
            for (int cc = b * NCHUNK; cc < cidx; ++cc)
                acc += cNeg[(size_t)cc * OUT_DIM + o];
#pragma unroll
            for (int r = 0; r < CHUNK; ++r) {
                PreH[(pb + r0 + r) * OUT_DIM + o] = acc;
                acc = fmaf(sh.s.wn[u][r], sh.s.hs[u][r][o], acc);
            }
            if (c == NCHUNK - 1) PreH[(pb + NN) * OUT_DIM + o] = acc;
        } else {
            int o = t2 - 128;
            float acc = 0.f;
            for (int cc = cidx + 1; cc < (b + 1) * NCHUNK; ++cc)
                acc += cPos[(size_t)cc * OUT_DIM + o];
#pragma unroll
            for (int r = CHUNK - 1; r >= 0; --r) {
                acc = fmaf(sh.s.wp[u][r], sh.s.hs[u][r][o], acc);
                SufH[(pb + r0 + r) * OUT_DIM + o] = acc;
            }
            if (c == NCHUNK - 1) SufH[(pb + NN) * OUT_DIM + o] = 0.f;
        }
        if (t2 == 0) {
            float a = 0.f;
            for (int cc = b * NCHUNK; cc < cidx; ++cc) a += cNegW[cc];
            for (int r = 0; r < CHUNK; ++r) { PreW[pb + r0 + r] = a; a += sh.s.wn[u][r]; }
            if (c == NCHUNK - 1) PreW[pb + NN] = a;
        }
        if (t2 == 128) {
            float a = 0.f;
            for (int cc = cidx + 1; cc < (b + 1) * NCHUNK; ++cc) a += cPosW[cc];
            for (int r = CHUNK - 1; r >= 0; --r) { a += sh.s.wp[u][r]; SufW[pb + r0 + r] = a; }
            if (c == NCHUNK - 1) SufW[pb + NN] = 0.f;
        }
    }
    __threadfence();
    grid.sync();

    // ================= P5: per-query combine =================
    {
        const int b  = blockIdx.x >> 5;
        const int q0 = vb * 32;
        const size_t pb = (size_t)b * (NN + 1);
        const float4* sd4 = (const float4*)(sorted_d + b * NN);
        {
            float4 v = sd4[tid];           // 512 threads x float4 = 2048
            *(float4*)&sh.q.sd[tid * 4] = v;
        }
        __syncthreads();
        if (t2 < 32) {
            int qv = q0 + t2;
            float sv = src[qv];
            float t = -sv;
            int lo = 0, hi = NN;
            while (lo < hi) {
                int mid = (lo + hi) >> 1;
                if (sh.q.sd[mid] > t) hi = mid; else lo = mid + 1;
            }
            float pe = expf(sv), pn = expf(0.2f * sv);
            float den = pe * SufW[pb + lo] + pn * PreW[pb + lo];
            sh.q.lo[u][t2] = lo;
            sh.q.pe[u][t2] = pe;
            sh.q.pn[u][t2] = pn;
            sh.q.sc[u][t2] = (den > 0.f) ? 1.f / den : 0.f;
        }
        __syncthreads();
        const int o  = t2 & 127;
        const int qh = t2 >> 7;
#pragma unroll 4
        for (int ps = 0; ps < 16; ++ps) {
            int ql = ps * 2 + qh;
            size_t base = pb + sh.q.lo[u][ql];
            float num = sh.q.pe[u][ql] * SufH[base * OUT_DIM + o] + sh.q.pn[u][ql] * PreH[base * OUT_DIM + o];
            out[(size_t)(q0 + ql) * OUT_DIM + o] = num * sh.q.sc[u][ql];
        }
    }
}

// ================================================================
// Fallback path: round-3 proven multi-kernel pipeline (74.9 us)
// ================================================================
__global__ __launch_bounds__(256) void fb_gemm_kernel(
    const float* __restrict__ x, const float* __restrict__ W,
    const float* __restrict__ a_src, const float* __restrict__ a_dst,
    float* __restrict__ h, float* __restrict__ src, float* __restrict__ dstv)
{
    __shared__ float xs[32][68];
    __shared__ float wsh[32][132];
    __shared__ float redS[64][16];
    __shared__ float redD[64][16];
    const int tid = threadIdx.x;
    const int m0 = blockIdx.x * 64;
    const int mt = tid >> 4;
    const int ot = tid & 15;
    float acc[4][8];
#pragma unroll
    for (int i = 0; i < 4; ++i)
#pragma unroll
        for (int j = 0; j < 8; ++j) acc[i][j] = 0.f;
    const float4* x4 = (const float4*)x;
    const float4* W4 = (const float4*)W;
    for (int k0 = 0; k0 < IN_DIM; k0 += 32) {
#pragma unroll
        for (int it = 0; it < 2; ++it) {
            int row = it * 32 + (tid >> 3);
            int c4 = tid & 7;
            float4 v = x4[(size_t)(m0 + row) * (IN_DIM / 4) + (k0 >> 2) + c4];
            xs[c4 * 4 + 0][row] = v.x; xs[c4 * 4 + 1][row] = v.y;
            xs[c4 * 4 + 2][row] = v.z; xs[c4 * 4 + 3][row] = v.w;
        }
#pragma unroll
        for (int it = 0; it < 4; ++it) {
            int idx = tid + it * 256;
            int o = idx >> 3;
            int c4 = idx & 7;
            float4 v = W4[(size_t)o * (IN_DIM / 4) + (k0 >> 2) + c4];
            wsh[c4 * 4 + 0][o] = v.x; wsh[c4 * 4 + 1][o] = v.y;
            wsh[c4 * 4 + 2][o] = v.z; wsh[c4 * 4 + 3][o] = v.w;
        }
        __syncthreads();
#pragma unroll
        for (int k = 0; k < 32; ++k) {
            float4 xv = *(const float4*)&xs[k][mt * 4];
            float4 wa = *(const float4*)&wsh[k][ot * 8];
            float4 wb = *(const float4*)&wsh[k][ot * 8 + 4];
            float xm[4] = {xv.x, xv.y, xv.z, xv.w};
            float wv[8] = {wa.x, wa.y, wa.z, wa.w, wb.x, wb.y, wb.z, wb.w};
#pragma unroll
            for (int i = 0; i < 4; ++i)
#pragma unroll
                for (int j = 0; j < 8; ++j)
                    acc[i][j] = fmaf(xm[i], wv[j], acc[i][j]);
        }
        __syncthreads();
    }
    float as8[8], ad8[8];
#pragma unroll
    for (int j = 0; j < 8; ++j) { as8[j] = a_src[ot * 8 + j]; ad8[j] = a_dst[ot * 8 + j]; }
#pragma unroll
    for (int i = 0; i < 4; ++i) {
        int m = m0 + mt * 4 + i;
        float4 v0 = {acc[i][0], acc[i][1], acc[i][2], acc[i][3]};
        float4 v1 = {acc[i][4], acc[i][5], acc[i][6], acc[i][7]};
        ((float4*)h)[(size_t)m * (OUT_DIM / 4) + ot * 2 + 0] = v0;
        ((float4*)h)[(size_t)m * (OUT_DIM / 4) + ot * 2 + 1] = v1;
        float ps = 0.f, pd = 0.f;
#pragma unroll
        for (int j = 0; j < 8; ++j) {
            ps = fmaf(acc[i][j], as8[j], ps);
            pd = fmaf(acc[i][j], ad8[j], pd);
        }
        redS[mt * 4 + i][ot] = ps;
        redD[mt * 4 + i][ot] = pd;
    }
    __syncthreads();
    if (tid < 64) {
        float ss = 0.f, dd = 0.f;
#pragma unroll
        for (int t = 0; t < 16; ++t) { ss += redS[tid][t]; dd += redD[tid][t]; }
        src[m0 + tid] = ss;
        dstv[m0 + tid] = dd;
    }
}

__global__ __launch_bounds__(256) void fb_rankpart_kernel(
    const float* __restrict__ dstv, int* __restrict__ rpart)
{
    __shared__ float ld[256];
    int blk = blockIdx.x;
    int b  = blk >> 6;
    int jc = (blk >> 3) & 7;
    int kc = blk & 7;
    const float* db = dstv + b * NN;
    ld[threadIdx.x] = db[kc * 256 + threadIdx.x];
    __syncthreads();
    int j = jc * 256 + threadIdx.x;
    float myd = db[j];
    int base = kc * 256;
    int rank = 0;
    const float4* l4 = (const float4*)ld;
#pragma unroll 8
    for (int q = 0; q < 64; ++q) {
        float4 v = l4[q];
        int jj = base + q * 4;
        rank += (v.x < myd) || (v.x == myd && jj + 0 < j);
        rank += (v.y < myd) || (v.y == myd && jj + 1 < j);
        rank += (v.z < myd) || (v.z == myd && jj + 2 < j);
        rank += (v.w < myd) || (v.w == myd && jj + 3 < j);
    }
    rpart[((size_t)b * NN + j) * 8 + kc] = rank;
}

__global__ __launch_bounds__(256) void fb_rankcombine_kernel(
    const float* __restrict__ dstv, const int* __restrict__ mask,
    const int* __restrict__ rpart,
    float* __restrict__ sorted_d, int* __restrict__ sorted_idx,
    float* __restrict__ wpos, float* __restrict__ wneg)
{
    int j = blockIdx.x * 256 + threadIdx.x;
    int b = j >> 11;
    const int4* rp = (const int4*)(rpart + (size_t)j * 8);
    int4 r0 = rp[0], r1 = rp[1];
    int rank = r0.x + r0.y + r0.z + r0.w + r1.x + r1.y + r1.z + r1.w;
    float myd = dstv[j];
    int lj = j & (NN - 1);
    sorted_d[b * NN + rank]   = myd;
    sorted_idx[b * NN + rank] = lj;
    int mk = mask[j];
    wpos[b * NN + rank] = mk ? expf(myd) : 0.f;
    wneg[b * NN + rank] = mk ? expf(0.2f * myd) : 0.f;
}

__global__ __launch_bounds__(128) void fb_chunksum_kernel(
    const float* __restrict__ h, const int* __restrict__ sidx,
    const float* __restrict__ wpos, const float* __restrict__ wneg,
    float* __restrict__ cPos, float* __restrict__ cNeg,
    float* __restrict__ cPosW, float* __restrict__ cNegW)
{
    int b = blockIdx.x / NCHUNK;
    int c = blockIdx.x % NCHUNK;
    int o = threadIdx.x;
    int r0 = c * CHUNK;
    float ap = 0.f, an = 0.f, apw = 0.f, anw = 0.f;
    for (int r = 0; r < CHUNK; ++r) {
        int rr = b * NN + r0 + r;
        int jj = sidx[rr];
        float wp = wpos[rr], wn = wneg[rr];
        float hv = h[((size_t)b * NN + jj) * OUT_DIM + o];
        ap = fmaf(wp, hv, ap);
        an = fmaf(wn, hv, an);
        apw += wp; anw += wn;
    }
    int cidx = b * NCHUNK + c;
    cPos[(size_t)cidx * OUT_DIM + o] = ap;
    cNeg[(size_t)cidx * OUT_DIM + o] = an;
    if (o == 0) { cPosW[cidx] = apw; cNegW[cidx] = anw; }
}

__global__ __launch_bounds__(128) void fb_scanwrite_kernel(
    const float* __restrict__ h, const int* __restrict__ sidx,
    const float* __restrict__ wpos, const float* __restrict__ wneg,
    const float* __restrict__ cPos, const float* __restrict__ cNeg,
    const float* __restrict__ cPosW, const float* __restrict__ cNegW,
    float* __restrict__ PreH, float* __restrict__ SufH,
    float* __restrict__ PreW, float* __restrict__ SufW)
{
    __shared__ float hs[CHUNK][OUT_DIM];
    __shared__ float wn_s[CHUNK], wp_s[CHUNK];
    __shared__ int   si_s[CHUNK];
    int b = blockIdx.x / NCHUNK;
    int c = blockIdx.x % NCHUNK;
    int o = threadIdx.x;
    int r0 = c * CHUNK;
    size_t hb = (size_t)b * NN;
    size_t pb = (size_t)b * (NN + 1);

    if (o < CHUNK) {
        int rr = b * NN + r0 + o;
        si_s[o] = sidx[rr];
        wn_s[o] = wneg[rr];
        wp_s[o] = wpos[rr];
    }
    __syncthreads();
#pragma unroll
    for (int it = 0; it < 8; ++it) {
        int row = it * 4 + (o >> 5);
        int c4 = o & 31;
        float4 v = ((const float4*)h)[(hb + si_s[row]) * (OUT_DIM / 4) + c4];
        *(float4*)&hs[row][c4 * 4] = v;
    }
    float bn = 0.f, bp = 0.f;
    for (int cc = 0; cc < c; ++cc)
        bn += cNeg[(size_t)(b * NCHUNK + cc) * OUT_DIM + o];
    for (int cc = c + 1; cc < NCHUNK; ++cc)
        bp += cPos[(size_t)(b * NCHUNK + cc) * OUT_DIM + o];
    __syncthreads();

    float acc = bn;
#pragma unroll
    for (int r = 0; r < CHUNK; ++r) {
        PreH[(pb + r0 + r) * OUT_DIM + o] = acc;
        acc = fmaf(wn_s[r], hs[r][o], acc);
    }
    if (c == NCHUNK - 1) PreH[(pb + NN) * OUT_DIM + o] = acc;

    float accp = bp;
#pragma unroll
    for (int r = CHUNK - 1; r >= 0; --r) {
        accp = fmaf(wp_s[r], hs[r][o], accp);
        SufH[(pb + r0 + r) * OUT_DIM + o] = accp;
    }
    if (c == NCHUNK - 1) SufH[(pb + NN) * OUT_DIM + o] = 0.f;

    if (o == 0) {
        float a = 0.f;
        for (int cc = 0; cc < c; ++cc) a += cNegW[b * NCHUNK + cc];
        for (int r = 0; r < CHUNK; ++r) { PreW[pb + r0 + r] = a; a += wn_s[r]; }
        if (c == NCHUNK - 1) PreW[pb + NN] = a;
    }
    if (o == 1) {
        float a = 0.f;
        for (int cc = c + 1; cc < NCHUNK; ++cc) a += cPosW[b * NCHUNK + cc];
        for (int r = CHUNK - 1; r >= 0; --r) { a += wp_s[r]; SufW[pb + r0 + r] = a; }
        if (c == NCHUNK - 1) SufW[pb + NN] = 0.f;
    }
}

__global__ __launch_bounds__(256) void fb_query_kernel(
    const float* __restrict__ src, const float* __restrict__ sorted_d,
    const float* __restrict__ PreH, const float* __restrict__ SufH,
    const float* __restrict__ PreW, const float* __restrict__ SufW,
    float* __restrict__ out)
{
    __shared__ float sd_s[NN];
    __shared__ int   lo_s[64];
    __shared__ float pe_s[64], pn_s[64], sc_s[64];
    const int tid = threadIdx.x;
    const int q0 = blockIdx.x * 64;
    const int b  = blockIdx.x >> 5;
    const size_t pb = (size_t)b * (NN + 1);
    const float4* sd4 = (const float4*)(sorted_d + b * NN);
#pragma unroll
    for (int it = 0; it < 2; ++it) {
        float4 v = sd4[it * 256 + tid];
        *(float4*)&sd_s[(it * 256 + tid) * 4] = v;
    }
    __syncthreads();
    if (tid < 64) {
        int q = q0 + tid;
        float s = src[q];
        float t = -s;
        int lo = 0, hi = NN;
        while (lo < hi) {
            int mid = (lo + hi) >> 1;
            if (sd_s[mid] > t) hi = mid; else lo = mid + 1;
        }
        float pe = expf(s), pn = expf(0.2f * s);
        float den = pe * SufW[pb + lo] + pn * PreW[pb + lo];
        lo_s[tid] = lo;
        pe_s[tid] = pe;
        pn_s[tid] = pn;
        sc_s[tid] = (den > 0.f) ? 1.f / den : 0.f;
    }
    __syncthreads();
    const int o  = tid & 127;
    const int qh = tid >> 7;
#pragma unroll 4
    for (int ps = 0; ps < 32; ++ps) {
        int ql = ps * 2 + qh;
        size_t base = pb + lo_s[ql];
        float num = pe_s[ql] * SufH[base * OUT_DIM + o] + pn_s[ql] * PreH[base * OUT_DIM + o];
        out[(size_t)(q0 + ql) * OUT_DIM + o] = num * sc_s[ql];
    }
}

// ---------------- launcher ----------------
extern "C" void kernel_launch(void* const* d_in, const int* in_sizes, int n_in,
                              void* d_out, int out_size, void* d_ws, size_t ws_size,
                              hipStream_t stream)
{
    const float* x     = (const float*)d_in[0];
    const int*   mask  = (const int*)d_in[1];
    const float* W     = (const float*)d_in[2];
    const float* a_src = (const float*)d_in[3];
    const float* a_dst = (const float*)d_in[4];
    float* out = (float*)d_out;
    float* ws  = (float*)d_ws;

    float* h        = ws + OFF_H;
    float* src      = ws + OFF_SRC;
    float* dstv     = ws + OFF_DST;
    float* sorted_d = ws + OFF_SD;
    int*   sidx     = (int*)(ws + OFF_SI);
    float* wpos     = ws + OFF_WP;
    float* wneg     = ws + OFF_WN;
    float* cPos     = ws + OFF_CP;
    float* cNeg     = ws + OFF_CN;
    float* cPosW    = ws + OFF_CPW;
    float* cNegW    = ws + OFF_CNW;
    float* PreH     = ws + OFF_PREH;
    float* SufH     = ws + OFF_SUFH;
    float* PreW     = ws + OFF_PREW;
    float* SufW     = ws + OFF_SUFW;
    int*   rpart    = (int*)(ws + OFF_RP);

    void* args[] = {
        (void*)&x, (void*)&mask, (void*)&W, (void*)&a_src, (void*)&a_dst,
        (void*)&h, (void*)&src, (void*)&dstv,
        (void*)&sorted_d, (void*)&sidx, (void*)&wpos, (void*)&wneg,
        (void*)&cPos, (void*)&cNeg, (void*)&cPosW, (void*)&cNegW,
        (void*)&PreH, (void*)&SufH, (void*)&PreW, (void*)&SufW,
        (void*)&out
    };
    hipError_t err = hipLaunchCooperativeKernel((const void*)fused_gat_kernel,
                                                dim3(NBLK), dim3(512), args, 0, stream);
    if (err != hipSuccess) {
        // Fallback: proven multi-kernel pipeline
        fb_gemm_kernel<<<M_TOT / 64, 256, 0, stream>>>(x, W, a_src, a_dst, h, src, dstv);
        fb_rankpart_kernel<<<BB * 64, 256, 0, stream>>>(dstv, rpart);
        fb_rankcombine_kernel<<<M_TOT / 256, 256, 0, stream>>>(dstv, mask, rpart, sorted_d, sidx, wpos, wneg);
        fb_chunksum_kernel<<<BB * NCHUNK, 128, 0, stream>>>(h, sidx, wpos, wneg, cPos, cNeg, cPosW, cNegW);
        fb_scanwrite_kernel<<<BB * NCHUNK, 128, 0, stream>>>(h, sidx, wpos, wneg, cPos, cNeg, cPosW, cNegW,
                                                             PreH, SufH, PreW, SufW);
        fb_query_kernel<<<M_TOT / 64, 256, 0, stream>>>(src, sorted_d, PreH, SufH, PreW, SufW, out);
    }
}

// Round 6
// 73.074 us; speedup vs baseline: 5.6417x; 5.6417x over previous
//
#include <hip/hip_runtime.h>
#include <math.h>

#define BB 8
#define NN 2048
#define IN_DIM 256
#define OUT_DIM 128
#define M_TOT (BB*NN)          // 16384
#define CHUNK 32
#define NCHUNK (NN/CHUNK)      // 64
#define LDP 264                // padded rank-chunk stride (floats): 8-way -> 2-way banks

// ---------------- workspace layout (in floats) ----------------
static const size_t OFF_H    = 0;                                   // h: M_TOT*128
static const size_t OFF_SRC  = OFF_H   + (size_t)M_TOT*OUT_DIM;
static const size_t OFF_DST  = OFF_SRC + M_TOT;
static const size_t OFF_SD   = OFF_DST + M_TOT;                     // sorted_d
static const size_t OFF_SI   = OFF_SD  + M_TOT;                     // sorted_idx (int)
static const size_t OFF_WP   = OFF_SI  + M_TOT;                     // wpos (sorted order)
static const size_t OFF_WN   = OFF_WP  + M_TOT;                     // wneg
static const size_t OFF_CP   = OFF_WN  + M_TOT;                     // chunk sums
static const size_t OFF_CN   = OFF_CP  + (size_t)BB*NCHUNK*OUT_DIM;
static const size_t OFF_CPW  = OFF_CN  + (size_t)BB*NCHUNK*OUT_DIM;
static const size_t OFF_CNW  = OFF_CPW + BB*NCHUNK;
static const size_t OFF_PREH = OFF_CNW + BB*NCHUNK;                 // 8*2049*128
static const size_t OFF_SUFH = OFF_PREH + (size_t)BB*(NN+1)*OUT_DIM;
static const size_t OFF_PREW = OFF_SUFH + (size_t)BB*(NN+1)*OUT_DIM;
static const size_t OFF_SUFW = OFF_PREW + (size_t)BB*(NN+1);

// ---------------- Kernel A: h = x @ W^T, plus src/dst dots ----------------
// 512 blocks x 256 thr, 32-row tiles, 2 blocks/CU.
__global__ __launch_bounds__(256, 2) void gat_gemm_kernel(
    const float* __restrict__ x, const float* __restrict__ W,
    const float* __restrict__ a_src, const float* __restrict__ a_dst,
    float* __restrict__ h, float* __restrict__ src, float* __restrict__ dstv)
{
    __shared__ float xs[32][34];     // [k][m] (34: 2-way staging, 8B-aligned rows)
    __shared__ float wsh[32][132];   // [k][o] (reads at ot*4 / 64+ot*4: 2-way, free)
    __shared__ float redS[32][16];
    __shared__ float redD[32][16];
    const int tid = threadIdx.x;
    const int m0 = blockIdx.x * 32;
    const int mt = tid >> 4;   // 0..15 -> 2 rows each
    const int ot = tid & 15;   // 0..15 -> cols ot*4..+3 and 64+ot*4..+3
    float acc[2][8];
#pragma unroll
    for (int i = 0; i < 2; ++i)
#pragma unroll
        for (int j = 0; j < 8; ++j) acc[i][j] = 0.f;

    const float4* x4 = (const float4*)x;
    const float4* W4 = (const float4*)W;

    for (int k0 = 0; k0 < IN_DIM; k0 += 32) {
        {   // x tile: 32 rows x 32 k, transposed into xs[k][m]; 1 float4/thread
            int row = tid >> 3, c4 = tid & 7;
            float4 v = x4[(size_t)(m0 + row) * (IN_DIM / 4) + (k0 >> 2) + c4];
            xs[c4 * 4 + 0][row] = v.x; xs[c4 * 4 + 1][row] = v.y;
            xs[c4 * 4 + 2][row] = v.z; xs[c4 * 4 + 3][row] = v.w;
        }
#pragma unroll
        for (int it = 0; it < 4; ++it) {   // W tile: 128 o x 32 k
            int idx = tid + it * 256;
            int o = idx >> 3, c4 = idx & 7;
            float4 v = W4[(size_t)o * (IN_DIM / 4) + (k0 >> 2) + c4];
            wsh[c4 * 4 + 0][o] = v.x; wsh[c4 * 4 + 1][o] = v.y;
            wsh[c4 * 4 + 2][o] = v.z; wsh[c4 * 4 + 3][o] = v.w;
        }
        __syncthreads();
#pragma unroll
        for (int k = 0; k < 32; ++k) {
            float2 xv = *(const float2*)&xs[k][mt * 2];
            float4 wa = *(const float4*)&wsh[k][ot * 4];
            float4 wb = *(const float4*)&wsh[k][64 + ot * 4];
            float xm[2] = {xv.x, xv.y};
            float wv[8] = {wa.x, wa.y, wa.z, wa.w, wb.x, wb.y, wb.z, wb.w};
#pragma unroll
            for (int i = 0; i < 2; ++i)
#pragma unroll
                for (int j = 0; j < 8; ++j)
                    acc[i][j] = fmaf(xm[i], wv[j], acc[i][j]);
        }
        __syncthreads();
    }

    // epilogue: store h tile + partial src/dst dots
    float as8[8], ad8[8];
#pragma unroll
    for (int j = 0; j < 4; ++j) {
        as8[j]     = a_src[ot * 4 + j];      ad8[j]     = a_dst[ot * 4 + j];
        as8[4 + j] = a_src[64 + ot * 4 + j]; ad8[4 + j] = a_dst[64 + ot * 4 + j];
    }
#pragma unroll
    for (int i = 0; i < 2; ++i) {
        int m = m0 + mt * 2 + i;
        float4 v0 = {acc[i][0], acc[i][1], acc[i][2], acc[i][3]};
        float4 v1 = {acc[i][4], acc[i][5], acc[i][6], acc[i][7]};
        ((float4*)h)[(size_t)m * (OUT_DIM / 4) + ot] = v0;
        ((float4*)h)[(size_t)m * (OUT_DIM / 4) + 16 + ot] = v1;
        float ps = 0.f, pd = 0.f;
#pragma unroll
        for (int j = 0; j < 8; ++j) {
            ps = fmaf(acc[i][j], as8[j], ps);
            pd = fmaf(acc[i][j], ad8[j], pd);
        }
        redS[mt * 2 + i][ot] = ps;
        redD[mt * 2 + i][ot] = pd;
    }
    __syncthreads();
    if (tid < 32) {
        float ss = 0.f, dd = 0.f;
#pragma unroll
        for (int t = 0; t < 16; ++t) { ss += redS[tid][t]; dd += redD[tid][t]; }
        src[m0 + tid] = ss;
        dstv[m0 + tid] = dd;
    }
}

// ---------------- Kernel R: fused rank + scatter + weights ----------------
// 512 blocks x 256 thr: block = (batch b, group of 32 j); 8 threads per j.
__global__ __launch_bounds__(256) void rank_kernel(
    const float* __restrict__ dstv, const int* __restrict__ mask,
    float* __restrict__ sorted_d, int* __restrict__ sorted_idx,
    float* __restrict__ wpos, float* __restrict__ wneg)
{
    __shared__ float ld[8 * LDP];     // padded: chunk q at q*LDP
    __shared__ int   red[32][8];
    const int tid = threadIdx.x;
    const int b  = blockIdx.x >> 6;   // 64 blocks per batch
    const int jg = blockIdx.x & 63;   // group of 32 j
    for (int i = tid; i < NN; i += 256)
        ld[(i >> 8) * LDP + (i & 255)] = dstv[b * NN + i];
    __syncthreads();
    const int js = tid >> 3;          // 0..31
    const int qq = tid & 7;           // jj-chunk
    const int jloc = jg * 32 + js;
    float myd = ld[(jloc >> 8) * LDP + (jloc & 255)];
    const float4* l4 = (const float4*)&ld[qq * LDP];
    int rank = 0;
#pragma unroll 8
    for (int t = 0; t < 64; ++t) {
        float4 v = l4[t];
        int jj = qq * 256 + t * 4;
        rank += (v.x < myd) || (v.x == myd && jj + 0 < jloc);
        rank += (v.y < myd) || (v.y == myd && jj + 1 < jloc);
        rank += (v.z < myd) || (v.z == myd && jj + 2 < jloc);
        rank += (v.w < myd) || (v.w == myd && jj + 3 < jloc);
    }
    red[js][qq] = rank;
    __syncthreads();
    if (tid < 32) {
        int j = jg * 32 + tid;
        const int* rr = red[tid];
        int rk = rr[0] + rr[1] + rr[2] + rr[3] + rr[4] + rr[5] + rr[6] + rr[7];
        float d = ld[(j >> 8) * LDP + (j & 255)];
        int mk = mask[b * NN + j];
        sorted_d[b * NN + rk] = d;
        sorted_idx[b * NN + rk] = j;
        wpos[b * NN + rk] = mk ? expf(d) : 0.f;
        wneg[b * NN + rk] = mk ? expf(0.2f * d) : 0.f;
    }
}

// ---------------- Kernel D1: per-chunk sums ----------------
__global__ __launch_bounds__(128) void chunksum_kernel(
    const float* __restrict__ h, const int* __restrict__ sidx,
    const float* __restrict__ wpos, const float* __restrict__ wneg,
    float* __restrict__ cPos, float* __restrict__ cNeg,
    float* __restrict__ cPosW, float* __restrict__ cNegW)
{
    int b = blockIdx.x / NCHUNK;
    int c = blockIdx.x % NCHUNK;
    int o = threadIdx.x;
    int r0 = c * CHUNK;
    float ap = 0.f, an = 0.f, apw = 0.f, anw = 0.f;
    for (int r = 0; r < CHUNK; ++r) {
        int rr = b * NN + r0 + r;
        int jj = sidx[rr];
        float wp = wpos[rr], wn = wneg[rr];
        float hv = h[((size_t)b * NN + jj) * OUT_DIM + o];
        ap = fmaf(wp, hv, ap);
        an = fmaf(wn, hv, an);
        apw += wp; anw += wn;
    }
    int cidx = b * NCHUNK + c;
    cPos[(size_t)cidx * OUT_DIM + o] = ap;
    cNeg[(size_t)cidx * OUT_DIM + o] = an;
    if (o == 0) { cPosW[cidx] = apw; cNegW[cidx] = anw; }
}

// ---------------- Kernel D3: fused cross-chunk prefix + expand ----------------
__global__ __launch_bounds__(128) void scanwrite_kernel(
    const float* __restrict__ h, const int* __restrict__ sidx,
    const float* __restrict__ wpos, const float* __restrict__ wneg,
    const float* __restrict__ cPos, const float* __restrict__ cNeg,
    const float* __restrict__ cPosW, const float* __restrict__ cNegW,
    float* __restrict__ PreH, float* __restrict__ SufH,
    float* __restrict__ PreW, float* __restrict__ SufW)
{
    __shared__ float hs[CHUNK][OUT_DIM];   // 16 KB
    __shared__ float wn_s[CHUNK], wp_s[CHUNK];
    __shared__ int   si_s[CHUNK];
    int b = blockIdx.x / NCHUNK;
    int c = blockIdx.x % NCHUNK;
    int o = threadIdx.x;
    int r0 = c * CHUNK;
    size_t hb = (size_t)b * NN;
    size_t pb = (size_t)b * (NN + 1);

    if (o < CHUNK) {
        int rr = b * NN + r0 + o;
        si_s[o] = sidx[rr];
        wn_s[o] = wneg[rr];
        wp_s[o] = wpos[rr];
    }
    __syncthreads();
#pragma unroll
    for (int it = 0; it < 8; ++it) {
        int row = it * 4 + (o >> 5);
        int c4 = o & 31;
        float4 v = ((const float4*)h)[(hb + si_s[row]) * (OUT_DIM / 4) + c4];
        *(float4*)&hs[row][c4 * 4] = v;
    }
    float bn = 0.f, bp = 0.f;
    for (int cc = 0; cc < c; ++cc)
        bn += cNeg[(size_t)(b * NCHUNK + cc) * OUT_DIM + o];
    for (int cc = c + 1; cc < NCHUNK; ++cc)
        bp += cPos[(size_t)(b * NCHUNK + cc) * OUT_DIM + o];
    __syncthreads();

    float acc = bn;
#pragma unroll
    for (int r = 0; r < CHUNK; ++r) {
        PreH[(pb + r0 + r) * OUT_DIM + o] = acc;
        acc = fmaf(wn_s[r], hs[r][o], acc);
    }
    if (c == NCHUNK - 1) PreH[(pb + NN) * OUT_DIM + o] = acc;

    float accp = bp;
#pragma unroll
    for (int r = CHUNK - 1; r >= 0; --r) {
        accp = fmaf(wp_s[r], hs[r][o], accp);
        SufH[(pb + r0 + r) * OUT_DIM + o] = accp;
    }
    if (c == NCHUNK - 1) SufH[(pb + NN) * OUT_DIM + o] = 0.f;

    if (o == 0) {
        float a = 0.f;
        for (int cc = 0; cc < c; ++cc) a += cNegW[b * NCHUNK + cc];
        for (int r = 0; r < CHUNK; ++r) { PreW[pb + r0 + r] = a; a += wn_s[r]; }
        if (c == NCHUNK - 1) PreW[pb + NN] = a;
    }
    if (o == 1) {
        float a = 0.f;
        for (int cc = c + 1; cc < NCHUNK; ++cc) a += cPosW[b * NCHUNK + cc];
        for (int r = CHUNK - 1; r >= 0; --r) { a += wp_s[r]; SufW[pb + r0 + r] = a; }
        if (c == NCHUNK - 1) SufW[pb + NN] = 0.f;
    }
}

// ---------------- Kernel E: per-query combine, 64 queries/block ----------------
__global__ __launch_bounds__(256) void query_kernel(
    const float* __restrict__ src, const float* __restrict__ sorted_d,
    const float* __restrict__ PreH, const float* __restrict__ SufH,
    const float* __restrict__ PreW, const float* __restrict__ SufW,
    float* __restrict__ out)
{
    __shared__ float sd_s[NN];       // 8 KB
    __shared__ int   lo_s[64];
    __shared__ float pe_s[64], pn_s[64], sc_s[64];
    const int tid = threadIdx.x;
    const int q0 = blockIdx.x * 64;
    const int b  = blockIdx.x >> 5;
    const size_t pb = (size_t)b * (NN + 1);
    const float4* sd4 = (const float4*)(sorted_d + b * NN);
#pragma unroll
    for (int it = 0; it < 2; ++it) {
        float4 v = sd4[it * 256 + tid];
        *(float4*)&sd_s[(it * 256 + tid) * 4] = v;
    }
    __syncthreads();
    if (tid < 64) {
        int q = q0 + tid;
        float s = src[q];
        float t = -s;
        int lo = 0, hi = NN;
        while (lo < hi) {
            int mid = (lo + hi) >> 1;
            if (sd_s[mid] > t) hi = mid; else lo = mid + 1;
        }
        float pe = expf(s), pn = expf(0.2f * s);
        float den = pe * SufW[pb + lo] + pn * PreW[pb + lo];
        lo_s[tid] = lo;
        pe_s[tid] = pe;
        pn_s[tid] = pn;
        sc_s[tid] = (den > 0.f) ? 1.f / den : 0.f;
    }
    __syncthreads();
    const int o  = tid & 127;
    const int qh = tid >> 7;
#pragma unroll 4
    for (int ps = 0; ps < 32; ++ps) {
        int ql = ps * 2 + qh;
        size_t base = pb + lo_s[ql];
        float num = pe_s[ql] * SufH[base * OUT_DIM + o] + pn_s[ql] * PreH[base * OUT_DIM + o];
        out[(size_t)(q0 + ql) * OUT_DIM + o] = num * sc_s[ql];
    }
}

// ---------------- launcher ----------------
extern "C" void kernel_launch(void* const* d_in, const int* in_sizes, int n_in,
                              void* d_out, int out_size, void* d_ws, size_t ws_size,
                              hipStream_t stream)
{
    const float* x     = (const float*)d_in[0];
    const int*   mask  = (const int*)d_in[1];
    const float* W     = (const float*)d_in[2];
    const float* a_src = (const float*)d_in[3];
    const float* a_dst = (const float*)d_in[4];
    float* out = (float*)d_out;
    float* ws  = (float*)d_ws;

    float* h        = ws + OFF_H;
    float* src      = ws + OFF_SRC;
    float* dstv     = ws + OFF_DST;
    float* sorted_d = ws + OFF_SD;
    int*   sidx     = (int*)(ws + OFF_SI);
    float* wpos     = ws + OFF_WP;
    float* wneg     = ws + OFF_WN;
    float* cPos     = ws + OFF_CP;
    float* cNeg     = ws + OFF_CN;
    float* cPosW    = ws + OFF_CPW;
    float* cNegW    = ws + OFF_CNW;
    float* PreH     = ws + OFF_PREH;
    float* SufH     = ws + OFF_SUFH;
    float* PreW     = ws + OFF_PREW;
    float* SufW     = ws + OFF_SUFW;

    gat_gemm_kernel<<<M_TOT / 32, 256, 0, stream>>>(x, W, a_src, a_dst, h, src, dstv);
    rank_kernel<<<BB * 64, 256, 0, stream>>>(dstv, mask, sorted_d, sidx, wpos, wneg);
    chunksum_kernel<<<BB * NCHUNK, 128, 0, stream>>>(h, sidx, wpos, wneg, cPos, cNeg, cPosW, cNegW);
    scanwrite_kernel<<<BB * NCHUNK, 128, 0, stream>>>(h, sidx, wpos, wneg, cPos, cNeg, cPosW, cNegW,
                                                      PreH, SufH, PreW, SufW);
    query_kernel<<<M_TOT / 64, 256, 0, stream>>>(src, sorted_d, PreH, SufH, PreW, SufW, out);
}